// Round 4
// baseline (8129.320 us; speedup 1.0000x reference)
//
#include <hip/hip_runtime.h>
#include <hip/hip_fp16.h>

#define N0C 200000
#define N1C 600000
#define N2C 400000
#define NRC (N0C + N1C + N2C)
#define RB0 0
#define RB1 N0C
#define RB2 (N0C + N1C)
#define NGC 128
#define D 32
#define SCAN_TILE 2048
#define NBLK 2048
#define NGRP (NBLK * 8)

// ---------- input fp32 -> fp16 ----------
__global__ void tohalf_kernel(const float* __restrict__ x, __half* __restrict__ o, size_t n4) {
    size_t t = (size_t)blockIdx.x * blockDim.x + threadIdx.x;
    size_t stride = (size_t)gridDim.x * blockDim.x;
    for (size_t i = t; i < n4; i += stride) {
        float4 v = reinterpret_cast<const float4*>(x)[i];
        __half2 h01 = __floats2half2_rn(v.x, v.y);
        __half2 h23 = __floats2half2_rn(v.z, v.w);
        reinterpret_cast<__half2*>(o)[2 * i] = h01;
        reinterpret_cast<__half2*>(o)[2 * i + 1] = h23;
    }
}

// ---------- CSR build ----------
__global__ void hist_kernel(const int* __restrict__ rows, int* __restrict__ counts, int nnz) {
    int e = blockIdx.x * blockDim.x + threadIdx.x;
    if (e >= nnz) return;
    atomicAdd(&counts[rows[e]], 1);
}

__global__ void scan_phase1(const int* __restrict__ counts, int* __restrict__ bsums, int n) {
    __shared__ int sd[256];
    int base = blockIdx.x * SCAN_TILE;
    int s = 0;
    for (int i = threadIdx.x; i < SCAN_TILE; i += 256) {
        int idx = base + i;
        s += (idx < n) ? counts[idx] : 0;
    }
    sd[threadIdx.x] = s;
    __syncthreads();
    for (int o = 128; o > 0; o >>= 1) {
        if (threadIdx.x < o) sd[threadIdx.x] += sd[threadIdx.x + o];
        __syncthreads();
    }
    if (threadIdx.x == 0) bsums[blockIdx.x] = sd[0];
}

__global__ void scan_phase2(int* __restrict__ bsums, int nb) {
    __shared__ int sd[1024];
    for (int i = threadIdx.x; i < nb; i += 256) sd[i] = bsums[i];
    __syncthreads();
    if (threadIdx.x == 0) {
        int acc = 0;
        for (int i = 0; i < nb; ++i) { int v = sd[i]; sd[i] = acc; acc += v; }
        bsums[nb] = acc;
    }
    __syncthreads();
    for (int i = threadIdx.x; i < nb; i += 256) bsums[i] = sd[i];
}

// writes rowptr AND cursor (scatter working copy)
__global__ void scan_phase3(const int* __restrict__ counts, const int* __restrict__ bsums,
                            int* __restrict__ rowptr, int* __restrict__ cursor, int n) {
    __shared__ int sd[256];
    int base = blockIdx.x * SCAN_TILE + threadIdx.x * 8;
    int v[8];
    int s = 0;
#pragma unroll
    for (int u = 0; u < 8; ++u) {
        int idx = base + u;
        int c = (idx < n) ? counts[idx] : 0;
        v[u] = s;
        s += c;
    }
    sd[threadIdx.x] = s;
    __syncthreads();
    if (threadIdx.x == 0) {
        int acc = bsums[blockIdx.x];
        for (int i = 0; i < 256; ++i) { int q = sd[i]; sd[i] = acc; acc += q; }
    }
    __syncthreads();
    int off = sd[threadIdx.x];
#pragma unroll
    for (int u = 0; u < 8; ++u) {
        int idx = base + u;
        if (idx < n) { int w = off + v[u]; rowptr[idx] = w; cursor[idx] = w; }
    }
}

__global__ void set_total_kernel(int* __restrict__ dst, const int* __restrict__ src) {
    *dst = *src;
}

// scatter with GLOBAL column index into the rank's merged CSR
__global__ void scatter_kernel(const int* __restrict__ rows, const int* __restrict__ cols,
                               const float* __restrict__ vals, int* __restrict__ cursor,
                               int2* __restrict__ cv, int nnz, int colbase) {
    int e = blockIdx.x * blockDim.x + threadIdx.x;
    if (e >= nnz) return;
    int r = rows[e];
    int pos = atomicAdd(&cursor[r], 1);
    cv[pos] = make_int2(cols[e] + colbase, __float_as_int(vals[e]));
}

// ---------- batched edge chunk: 8 metas -> 8 independent gathers -> predicated FMAs ----------
template <int DIN, int NM, bool PRED>
__device__ inline void do_chunk(const int2* __restrict__ cv, int k, int ke,
                                const __half* __restrict__ xact, int j,
                                int t1, int t2, float* aL, float* aH) {
    int2 e[8];
#pragma unroll
    for (int u = 0; u < 8; ++u) {
        if (PRED) e[u] = (k + u < ke) ? cv[k + u] : make_int2(0, 0);
        else e[u] = cv[k + u];
    }
    float xg[8], xh[8];
#pragma unroll
    for (int u = 0; u < 8; ++u) {
        const __half* p = xact + (size_t)e[u].x * DIN;
        xg[u] = __half2float(p[j]);
        if (DIN == 64) xh[u] = __half2float(p[32 + j]);
    }
#pragma unroll
    for (int u = 0; u < 8; ++u) {
        float bv = __int_as_float(e[u].y);
        int bc = e[u].x;
        float s0, s1, s2;
        if (NM == 2) { s0 = (bc < t1) ? bv : 0.f; s1 = bv - s0; s2 = 0.f; }
        else { s0 = (bc < t1) ? bv : 0.f; s2 = (bc >= t2) ? bv : 0.f; s1 = bv - s0 - s2; }
        aL[0] = fmaf(s0, xg[u], aL[0]);
        aL[1] = fmaf(s1, xg[u], aL[1]);
        if (NM == 3) aL[2] = fmaf(s2, xg[u], aL[2]);
        if (DIN == 64) {
            aH[0] = fmaf(s0, xh[u], aH[0]);
            aH[1] = fmaf(s1, xh[u], aH[1]);
            if (NM == 3) aH[2] = fmaf(s2, xh[u], aH[2]);
        }
    }
}

// ---------- fused rank kernel: persistent groups over contiguous row spans ----------
template <int DIN, int NM>
__global__ __launch_bounds__(256) void rank_kernel(
    const int* __restrict__ rp, const int2* __restrict__ cv,
    const float* __restrict__ Wa, const float* __restrict__ Wb,
    const float* __restrict__ Wc,
    int t1, int t2, const __half* __restrict__ xact,
    __half* __restrict__ outbuf, int rowbase, float scale, int n) {
    __shared__ float Ws[NM * DIN * 32];
    {
        const float* wg[3] = { Wa, Wb, Wc };
#pragma unroll
        for (int m = 0; m < NM; ++m)
            for (int i = threadIdx.x; i < DIN * 32; i += 256)
                Ws[m * DIN * 32 + i] = wg[m][i];
    }
    __syncthreads();
    int gid = (blockIdx.x * 256 + threadIdx.x) >> 5;
    int j = threadIdx.x & 31;
    int span = (n + NGRP - 1) / NGRP;
    int r0 = gid * span;
    int r1 = min(n, r0 + span);
    for (int row = r0; row < r1; ++row) {
        int ks = rp[row], ke = rp[row + 1];
        float aL[NM], aH[NM];
#pragma unroll
        for (int m = 0; m < NM; ++m) { aL[m] = 0.f; aH[m] = 0.f; }
        int k = ks;
        for (; k + 8 <= ke; k += 8)
            do_chunk<DIN, NM, false>(cv, k, ke, xact, j, t1, t2, aL, aH);
        if (k < ke)
            do_chunk<DIN, NM, true>(cv, k, ke, xact, j, t1, t2, aL, aH);
        // out[j] = relu(sum_m sum_k a_m[k] * W_m[k][j]) * scale
        float s = 0.f;
#pragma unroll
        for (int kk = 0; kk < 32; ++kk) {
#pragma unroll
            for (int m = 0; m < NM; ++m)
                s = fmaf(__shfl(aL[m], kk, 32), Ws[m * DIN * 32 + kk * 32 + j], s);
        }
        if (DIN == 64) {
#pragma unroll
            for (int kk = 0; kk < 32; ++kk) {
#pragma unroll
                for (int m = 0; m < NM; ++m)
                    s = fmaf(__shfl(aH[m], kk, 32), Ws[m * DIN * 32 + (kk + 32) * 32 + j], s);
            }
        }
        outbuf[(size_t)(rowbase + row) * 32 + j] = __float2half(fmaxf(s, 0.f) * scale);
    }
}

// ---------- pooling (batch sorted) ----------
__global__ void pool_kernel(const __half* __restrict__ x1, const int* __restrict__ batch,
                            float* __restrict__ sums, float* __restrict__ cnt, int n) {
    const int RPG = 512;
    int j = threadIdx.x & 31;
    int s = threadIdx.x >> 5;
    long long start = ((long long)blockIdx.x * 8 + s) * RPG;
    if (start >= n) return;
    long long end = start + RPG;
    if (end > n) end = n;
    int curg = batch[start];
    float a = 0.f, c = 0.f;
    for (long long r = start; r < end; ++r) {
        int g = batch[r];
        if (g != curg) {
            atomicAdd(&sums[(size_t)curg * D + j], a);
            if (j == 0) atomicAdd(&cnt[curg], c);
            a = 0.f; c = 0.f; curg = g;
        }
        a += fabsf(__half2float(x1[(size_t)r * D + j]));
        c += 1.f;
    }
    atomicAdd(&sums[(size_t)curg * D + j], a);
    if (j == 0) atomicAdd(&cnt[curg], c);
}

// ---------- head ----------
__global__ void head_kernel(const float* __restrict__ sums, const float* __restrict__ cnt,
                            const float* __restrict__ w1, const float* __restrict__ b1,
                            const float* __restrict__ w2, const float* __restrict__ b2,
                            float* __restrict__ out) {
    __shared__ float W1s[D * D], W2s[D * 10], B1s[D], B2s[10];
    int tid = threadIdx.x;
    for (int i = tid; i < D * D; i += blockDim.x) W1s[i] = w1[i];
    for (int i = tid; i < D * 10; i += blockDim.x) W2s[i] = w2[i];
    if (tid < D) B1s[tid] = b1[tid];
    if (tid < 10) B2s[tid] = b2[tid];
    __syncthreads();
    int g = tid;
    if (g >= NGC) return;
    float invc = 1.f / fmaxf(cnt[g], 1.f);
    float p[D];
#pragma unroll
    for (int k = 0; k < D; ++k) p[k] = sums[(size_t)g * D + k] * invc;
    float h[D];
#pragma unroll
    for (int j = 0; j < D; ++j) {
        float s = B1s[j];
#pragma unroll
        for (int k = 0; k < D; ++k) s = fmaf(p[k], W1s[k * D + j], s);
        h[j] = fmaxf(s, 0.f);
    }
    float l[10];
    float m = -1e30f;
#pragma unroll
    for (int o = 0; o < 10; ++o) {
        float s = B2s[o];
#pragma unroll
        for (int k = 0; k < D; ++k) s = fmaf(h[k], W2s[k * 10 + o], s);
        l[o] = s;
        m = fmaxf(m, s);
    }
    float den = 0.f;
#pragma unroll
    for (int o = 0; o < 10; ++o) { l[o] = expf(l[o] - m); den += l[o]; }
    float inv = 1.f / den;
#pragma unroll
    for (int o = 0; o < 10; ++o) out[g * 10 + o] = l[o] * inv;
}

extern "C" void kernel_launch(void* const* d_in, const int* in_sizes, int n_in,
                              void* d_out, int out_size, void* d_ws, size_t ws_size,
                              hipStream_t stream) {
    const float* X0 = (const float*)d_in[0];
    const float* X1 = (const float*)d_in[1];
    const float* X2 = (const float*)d_in[2];
    // mats: 0=L0,1=L1,2=L2,3=B2D3,4=D2B1TD1inv,5=D1invB1,6=B2TD2inv
    const int* spr[7]; const int* spc[7]; const float* spv[7]; int spn[7];
    for (int m = 0; m < 7; ++m) {
        spr[m] = (const int*)d_in[3 + m * 3];
        spc[m] = (const int*)d_in[4 + m * 3];
        spv[m] = (const float*)d_in[5 + m * 3];
        spn[m] = in_sizes[3 + m * 3];
    }
    const int* batch1 = (const int*)d_in[24];
    const float* W1 = (const float*)d_in[25];
    const float* W234 = (const float*)d_in[26];
    const float* mlp1_w = (const float*)d_in[27];
    const float* mlp1_b = (const float*)d_in[28];
    const float* mlp2_w = (const float*)d_in[29];
    const float* mlp2_b = (const float*)d_in[30];
    float* out = (float*)d_out;

    // column base of each mat's source in the concatenated activation buffer
    const int colbase_mat[7] = { RB0, RB1, RB2, RB2, RB0, RB1, RB1 };
    // per-rank merged CSR: rank0 <- {L0, D1invB1}; rank1 <- {D2B1TD1inv, L1, B2D3}; rank2 <- {B2TD2inv, L2}
    struct RankDef { int nrows; int nmats; int mats[3]; };
    const RankDef rdefs[3] = {
        { N0C, 2, { 0, 5, -1 } },
        { N1C, 3, { 4, 1, 3 } },
        { N2C, 2, { 6, 2, -1 } },
    };

    // ---- workspace carve ----
    char* wp = (char*)d_ws;
    __half* Xh64 = (__half*)wp;            wp += (size_t)NRC * 64 * sizeof(__half);
    __half* Ha = (__half*)wp;              wp += (size_t)NRC * 32 * sizeof(__half);
    __half* Hb = (__half*)wp;              wp += (size_t)NRC * 32 * sizeof(__half);
    size_t total_nnz = 0;
    for (int m = 0; m < 7; ++m) total_nnz += (size_t)spn[m];
    int2* cv_base = (int2*)wp;             wp += total_nnz * sizeof(int2);
    int* rowptr_base = (int*)wp;           wp += (size_t)(NRC + 3) * sizeof(int);
    int* counts = (int*)wp;                wp += (size_t)N1C * sizeof(int);
    int* cursor = (int*)wp;                wp += (size_t)N1C * sizeof(int);
    int* bsums = (int*)wp;                 wp += 1040 * sizeof(int);
    float* sums = (float*)wp;              wp += (size_t)NGC * D * sizeof(float);
    float* cnt = (float*)wp;               wp += (size_t)NGC * sizeof(float);

    // ---- inputs -> fp16 (concatenated [X0;X1;X2], stride 64) ----
    tohalf_kernel<<<2048, 256, 0, stream>>>(X0, Xh64 + (size_t)RB0 * 64, (size_t)N0C * 16);
    tohalf_kernel<<<2048, 256, 0, stream>>>(X1, Xh64 + (size_t)RB1 * 64, (size_t)N1C * 16);
    tohalf_kernel<<<2048, 256, 0, stream>>>(X2, Xh64 + (size_t)RB2 * 64, (size_t)N2C * 16);

    // ---- build 3 merged rank CSRs ----
    int* rp_r[3]; int2* cv_r[3];
    {
        size_t rpoff = 0, cvoff = 0;
        for (int r = 0; r < 3; ++r) {
            const RankDef& rd = rdefs[r];
            int nr = rd.nrows;
            rp_r[r] = rowptr_base + rpoff; rpoff += (size_t)nr + 1;
            cv_r[r] = cv_base + cvoff;
            int nb = (nr + SCAN_TILE - 1) / SCAN_TILE;
            hipMemsetAsync(counts, 0, (size_t)nr * sizeof(int), stream);
            for (int i = 0; i < rd.nmats; ++i) {
                int m = rd.mats[i];
                hist_kernel<<<(spn[m] + 255) / 256, 256, 0, stream>>>(spr[m], counts, spn[m]);
            }
            scan_phase1<<<nb, 256, 0, stream>>>(counts, bsums, nr);
            scan_phase2<<<1, 256, 0, stream>>>(bsums, nb);
            scan_phase3<<<nb, 256, 0, stream>>>(counts, bsums, rp_r[r], cursor, nr);
            set_total_kernel<<<1, 1, 0, stream>>>(rp_r[r] + nr, bsums + nb);
            for (int i = 0; i < rd.nmats; ++i) {
                int m = rd.mats[i];
                scatter_kernel<<<(spn[m] + 255) / 256, 256, 0, stream>>>(
                    spr[m], spc[m], spv[m], cursor, cv_r[r], spn[m], colbase_mat[m]);
                cvoff += (size_t)spn[m];
            }
        }
    }

    // ---- 4 layers ----
    __half* cur = Ha;
    __half* nxt = Hb;
    const int IMAX = 0x7fffffff;
    for (int l = 0; l < 4; ++l) {
        const __half* xact = (l == 0) ? Xh64 : cur;
        __half* dst = (l == 0) ? Ha : nxt;
        const float* Wl = (l == 0) ? W1 : W234 + (size_t)(l - 1) * 7 * 32 * 32;
        const size_t wst = (l == 0) ? (size_t)64 * 32 : (size_t)32 * 32;
#define WPK(k) (Wl + (size_t)(k) * wst)
        if (l == 0) {
            rank_kernel<64, 2><<<NBLK, 256, 0, stream>>>(
                rp_r[0], cv_r[0], WPK(0), WPK(3), nullptr, RB1, IMAX, xact, dst, RB0, 0.5f, N0C);
            rank_kernel<64, 3><<<NBLK, 256, 0, stream>>>(
                rp_r[1], cv_r[1], WPK(1), WPK(2), WPK(5), RB1, RB2, xact, dst, RB1, 1.f / 3.f, N1C);
            rank_kernel<64, 2><<<NBLK, 256, 0, stream>>>(
                rp_r[2], cv_r[2], WPK(4), WPK(6), nullptr, RB2, IMAX, xact, dst, RB2, 0.5f, N2C);
            cur = Ha; nxt = Hb;
        } else {
            rank_kernel<32, 2><<<NBLK, 256, 0, stream>>>(
                rp_r[0], cv_r[0], WPK(0), WPK(3), nullptr, RB1, IMAX, xact, dst, RB0, 0.5f, N0C);
            rank_kernel<32, 3><<<NBLK, 256, 0, stream>>>(
                rp_r[1], cv_r[1], WPK(1), WPK(2), WPK(5), RB1, RB2, xact, dst, RB1, 1.f / 3.f, N1C);
            rank_kernel<32, 2><<<NBLK, 256, 0, stream>>>(
                rp_r[2], cv_r[2], WPK(4), WPK(6), nullptr, RB2, IMAX, xact, dst, RB2, 0.5f, N2C);
            __half* t2 = cur; cur = nxt; nxt = t2;
        }
#undef WPK
    }

    hipMemsetAsync(sums, 0, (size_t)(NGC * D + NGC) * sizeof(float), stream);
    {
        int groups = (N1C + 511) / 512;
        int blocks = (groups + 7) / 8;
        pool_kernel<<<blocks, 256, 0, stream>>>(cur + (size_t)RB1 * 32, batch1, sums, cnt, N1C);
    }
    head_kernel<<<1, 128, 0, stream>>>(sums, cnt, mlp1_w, mlp1_b, mlp2_w, mlp2_b, out);
}

// Round 5
// 7264.028 us; speedup vs baseline: 1.1191x; 1.1191x over previous
//
#include <hip/hip_runtime.h>
#include <hip/hip_fp16.h>

#define N0C 200000
#define N1C 600000
#define N2C 400000
#define NRC (N0C + N1C + N2C)
#define NGC 128
#define D 32
#define SCAN_TILE 2048

// act buffer row bases (rank-concatenated)
#define AB0 0
#define AB1 N0C
#define AB2 (N0C + N1C)

// ---------- input fp32 -> fp16 ----------
__global__ void tohalf_kernel(const float* __restrict__ x, __half* __restrict__ o, size_t n4) {
    size_t t = (size_t)blockIdx.x * blockDim.x + threadIdx.x;
    size_t stride = (size_t)gridDim.x * blockDim.x;
    for (size_t i = t; i < n4; i += stride) {
        float4 v = reinterpret_cast<const float4*>(x)[i];
        __half2 h01 = __floats2half2_rn(v.x, v.y);
        __half2 h23 = __floats2half2_rn(v.z, v.w);
        reinterpret_cast<__half2*>(o)[2 * i] = h01;
        reinterpret_cast<__half2*>(o)[2 * i + 1] = h23;
    }
}

// ---------- CSR build ----------
__global__ void hist_kernel(const int* __restrict__ rows, int* __restrict__ counts, int nnz) {
    int e = blockIdx.x * blockDim.x + threadIdx.x;
    if (e >= nnz) return;
    atomicAdd(&counts[rows[e]], 1);
}

__global__ void scan_phase1(const int* __restrict__ counts, int* __restrict__ bsums, int n) {
    __shared__ int sd[256];
    int base = blockIdx.x * SCAN_TILE;
    int s = 0;
    for (int i = threadIdx.x; i < SCAN_TILE; i += 256) {
        int idx = base + i;
        s += (idx < n) ? counts[idx] : 0;
    }
    sd[threadIdx.x] = s;
    __syncthreads();
    for (int o = 128; o > 0; o >>= 1) {
        if (threadIdx.x < o) sd[threadIdx.x] += sd[threadIdx.x + o];
        __syncthreads();
    }
    if (threadIdx.x == 0) bsums[blockIdx.x] = sd[0];
}

__global__ void scan_phase2(int* __restrict__ bsums, int nb) {
    __shared__ int sd[1024];
    for (int i = threadIdx.x; i < nb; i += 256) sd[i] = bsums[i];
    __syncthreads();
    if (threadIdx.x == 0) {
        int acc = 0;
        for (int i = 0; i < nb; ++i) { int v = sd[i]; sd[i] = acc; acc += v; }
        bsums[nb] = acc;
    }
    __syncthreads();
    for (int i = threadIdx.x; i < nb; i += 256) bsums[i] = sd[i];
}

// writes rowptr AND cursor (scatter working copy)
__global__ void scan_phase3(const int* __restrict__ counts, const int* __restrict__ bsums,
                            int* __restrict__ rowptr, int* __restrict__ cursor, int n) {
    __shared__ int sd[256];
    int base = blockIdx.x * SCAN_TILE + threadIdx.x * 8;
    int v[8];
    int s = 0;
#pragma unroll
    for (int u = 0; u < 8; ++u) {
        int idx = base + u;
        int c = (idx < n) ? counts[idx] : 0;
        v[u] = s;
        s += c;
    }
    sd[threadIdx.x] = s;
    __syncthreads();
    if (threadIdx.x == 0) {
        int acc = bsums[blockIdx.x];
        for (int i = 0; i < 256; ++i) { int q = sd[i]; sd[i] = acc; acc += q; }
    }
    __syncthreads();
    int off = sd[threadIdx.x];
#pragma unroll
    for (int u = 0; u < 8; ++u) {
        int idx = base + u;
        if (idx < n) { int w = off + v[u]; rowptr[idx] = w; cursor[idx] = w; }
    }
}

__global__ void set_total_kernel(int* __restrict__ dst, const int* __restrict__ src) {
    *dst = *src;
}

// scatter with GLOBAL column index (into XWbuf row space)
__global__ void scatter_kernel(const int* __restrict__ rows, const int* __restrict__ cols,
                               const float* __restrict__ vals, int* __restrict__ cursor,
                               int2* __restrict__ cv, int nnz, int colbase) {
    int e = blockIdx.x * blockDim.x + threadIdx.x;
    if (e >= nnz) return;
    int r = rows[e];
    int pos = atomicAdd(&cursor[r], 1);
    cv[pos] = make_int2(cols[e] + colbase, __float_as_int(vals[e]));
}

// ---------- projection: XWslot[row, 32] = x[row, :DIN] @ W ----------
template <int DIN>
__global__ __launch_bounds__(256) void xw_kernel(const __half* __restrict__ x,
                                                 const float* __restrict__ W,
                                                 __half* __restrict__ o, int n) {
    __shared__ float Ws[DIN * 32];
    for (int i = threadIdx.x; i < DIN * 32; i += 256) Ws[i] = W[i];
    __syncthreads();
    int g = (blockIdx.x * 256 + threadIdx.x) >> 5;
    int j = threadIdx.x & 31;
    int gstride = (gridDim.x * 256) >> 5;
    for (int row = g; row < n; row += gstride) {
        float xlo = __half2float(x[(size_t)row * DIN + j]);
        float xhi = 0.f;
        if (DIN == 64) xhi = __half2float(x[(size_t)row * DIN + 32 + j]);
        float s = 0.f;
#pragma unroll
        for (int k = 0; k < 32; ++k)
            s = fmaf(__shfl(xlo, k, 32), Ws[k * 32 + j], s);
        if (DIN == 64) {
#pragma unroll
            for (int k = 0; k < 32; ++k)
                s = fmaf(__shfl(xhi, k, 32), Ws[(32 + k) * 32 + j], s);
        }
        o[(size_t)row * 32 + j] = __float2half(s);
    }
}

// ---------- pure gather: act[rowbase+g, j] = relu(sum_k v_k * XW[c_k, j]) * scale ----------
__global__ __launch_bounds__(256, 8) void gather_kernel(
    const int* __restrict__ rp, const int2* __restrict__ cv,
    const __half* __restrict__ XW, __half* __restrict__ act,
    int rowbase, float scale, int n) {
    int g = (blockIdx.x * 256 + threadIdx.x) >> 5;
    int j = threadIdx.x & 31;
    if (g >= n) return;
    int ks = rp[g], ke = rp[g + 1];
    float s = 0.f;
    for (int k = ks; k < ke; k += 16) {
        int idx[16]; float vv[16];
#pragma unroll
        for (int u = 0; u < 16; ++u) {
            int kk = k + u;
            idx[u] = (kk < ke) ? kk : (ke - 1);   // clamped: always a valid edge
        }
        int2 e[16];
#pragma unroll
        for (int u = 0; u < 16; ++u) e[u] = cv[idx[u]];
        float xg[16];
#pragma unroll
        for (int u = 0; u < 16; ++u)
            xg[u] = __half2float(XW[(size_t)e[u].x * 32 + j]);
#pragma unroll
        for (int u = 0; u < 16; ++u) {
            vv[u] = (k + u < ke) ? __int_as_float(e[u].y) : 0.f;
            s = fmaf(vv[u], xg[u], s);
        }
    }
    act[(size_t)(rowbase + g) * 32 + j] = __float2half(fmaxf(s, 0.f) * scale);
}

// ---------- pooling (batch sorted) ----------
__global__ void pool_kernel(const __half* __restrict__ x1, const int* __restrict__ batch,
                            float* __restrict__ sums, float* __restrict__ cnt, int n) {
    const int RPG = 512;
    int j = threadIdx.x & 31;
    int s = threadIdx.x >> 5;
    long long start = ((long long)blockIdx.x * 8 + s) * RPG;
    if (start >= n) return;
    long long end = start + RPG;
    if (end > n) end = n;
    int curg = batch[start];
    float a = 0.f, c = 0.f;
    for (long long r = start; r < end; ++r) {
        int g = batch[r];
        if (g != curg) {
            atomicAdd(&sums[(size_t)curg * D + j], a);
            if (j == 0) atomicAdd(&cnt[curg], c);
            a = 0.f; c = 0.f; curg = g;
        }
        a += fabsf(__half2float(x1[(size_t)r * D + j]));
        c += 1.f;
    }
    atomicAdd(&sums[(size_t)curg * D + j], a);
    if (j == 0) atomicAdd(&cnt[curg], c);
}

// ---------- head ----------
__global__ void head_kernel(const float* __restrict__ sums, const float* __restrict__ cnt,
                            const float* __restrict__ w1, const float* __restrict__ b1,
                            const float* __restrict__ w2, const float* __restrict__ b2,
                            float* __restrict__ out) {
    __shared__ float W1s[D * D], W2s[D * 10], B1s[D], B2s[10];
    int tid = threadIdx.x;
    for (int i = tid; i < D * D; i += blockDim.x) W1s[i] = w1[i];
    for (int i = tid; i < D * 10; i += blockDim.x) W2s[i] = w2[i];
    if (tid < D) B1s[tid] = b1[tid];
    if (tid < 10) B2s[tid] = b2[tid];
    __syncthreads();
    int g = tid;
    if (g >= NGC) return;
    float invc = 1.f / fmaxf(cnt[g], 1.f);
    float p[D];
#pragma unroll
    for (int k = 0; k < D; ++k) p[k] = sums[(size_t)g * D + k] * invc;
    float h[D];
#pragma unroll
    for (int j = 0; j < D; ++j) {
        float s = B1s[j];
#pragma unroll
        for (int k = 0; k < D; ++k) s = fmaf(p[k], W1s[k * D + j], s);
        h[j] = fmaxf(s, 0.f);
    }
    float l[10];
    float m = -1e30f;
#pragma unroll
    for (int o = 0; o < 10; ++o) {
        float s = B2s[o];
#pragma unroll
        for (int k = 0; k < D; ++k) s = fmaf(h[k], W2s[k * 10 + o], s);
        l[o] = s;
        m = fmaxf(m, s);
    }
    float den = 0.f;
#pragma unroll
    for (int o = 0; o < 10; ++o) { l[o] = expf(l[o] - m); den += l[o]; }
    float inv = 1.f / den;
#pragma unroll
    for (int o = 0; o < 10; ++o) out[g * 10 + o] = l[o] * inv;
}

extern "C" void kernel_launch(void* const* d_in, const int* in_sizes, int n_in,
                              void* d_out, int out_size, void* d_ws, size_t ws_size,
                              hipStream_t stream) {
    const float* X0 = (const float*)d_in[0];
    const float* X1 = (const float*)d_in[1];
    const float* X2 = (const float*)d_in[2];
    // mats: 0=L0,1=L1,2=L2,3=B2D3,4=D2B1TD1inv,5=D1invB1,6=B2TD2inv
    const int* spr[7]; const int* spc[7]; const float* spv[7]; int spn[7];
    for (int m = 0; m < 7; ++m) {
        spr[m] = (const int*)d_in[3 + m * 3];
        spc[m] = (const int*)d_in[4 + m * 3];
        spv[m] = (const float*)d_in[5 + m * 3];
        spn[m] = in_sizes[3 + m * 3];
    }
    const int* batch1 = (const int*)d_in[24];
    const float* W1 = (const float*)d_in[25];
    const float* W234 = (const float*)d_in[26];
    const float* mlp1_w = (const float*)d_in[27];
    const float* mlp1_b = (const float*)d_in[28];
    const float* mlp2_w = (const float*)d_in[29];
    const float* mlp2_b = (const float*)d_in[30];
    float* out = (float*)d_out;

    // per-mat: source act base (rank concat), XWbuf slot base, W index, src rows
    const int srcbase_mat[7] = { AB0, AB1, AB2, AB2, AB0, AB1, AB1 };
    const int srcrows_mat[7] = { N0C, N1C, N2C, N2C, N0C, N1C, N1C };
    const int wk_mat[7]      = { 0, 2, 6, 5, 1, 3, 4 };
    int XB[7];  // XWbuf slot bases
    {
        int acc = 0;
        for (int m = 0; m < 7; ++m) { XB[m] = acc; acc += srcrows_mat[m]; }
    }
    const int XWROWS = 3000000;

    // rank CSRs: rank0 <- {L0, D1invB1}; rank1 <- {D2B1TD1inv, L1, B2D3}; rank2 <- {B2TD2inv, L2}
    struct RankDef { int nrows; int nmats; int mats[3]; };
    const RankDef rdefs[3] = {
        { N0C, 2, { 0, 5, -1 } },
        { N1C, 3, { 4, 1, 3 } },
        { N2C, 2, { 6, 2, -1 } },
    };

    // ---- workspace carve ----
    char* wp = (char*)d_ws;
    __half* Xh64 = (__half*)wp;            wp += (size_t)NRC * 64 * sizeof(__half);   // 153.6MB
    __half* act = (__half*)wp;             wp += (size_t)NRC * 32 * sizeof(__half);   // 76.8MB
    __half* XWbuf = (__half*)wp;           wp += (size_t)XWROWS * 32 * sizeof(__half);// 192MB
    size_t total_nnz = 0;
    for (int m = 0; m < 7; ++m) total_nnz += (size_t)spn[m];
    int2* cv_base = (int2*)wp;             wp += total_nnz * sizeof(int2);            // 134.4MB
    int* rowptr_base = (int*)wp;           wp += (size_t)(NRC + 3) * sizeof(int);
    int* counts = (int*)wp;                wp += (size_t)N1C * sizeof(int);
    int* cursor = (int*)wp;                wp += (size_t)N1C * sizeof(int);
    int* bsums = (int*)wp;                 wp += 1040 * sizeof(int);
    float* sums = (float*)wp;              wp += (size_t)NGC * D * sizeof(float);
    float* cnt = (float*)wp;               wp += (size_t)NGC * sizeof(float);

    // ---- inputs -> fp16 (concatenated [X0;X1;X2], stride 64) ----
    tohalf_kernel<<<2048, 256, 0, stream>>>(X0, Xh64 + (size_t)AB0 * 64, (size_t)N0C * 16);
    tohalf_kernel<<<2048, 256, 0, stream>>>(X1, Xh64 + (size_t)AB1 * 64, (size_t)N1C * 16);
    tohalf_kernel<<<2048, 256, 0, stream>>>(X2, Xh64 + (size_t)AB2 * 64, (size_t)N2C * 16);

    // ---- build 3 merged rank CSRs (columns globalized into XWbuf row space) ----
    int* rp_r[3]; int2* cv_r[3];
    {
        size_t rpoff = 0, cvoff = 0;
        for (int r = 0; r < 3; ++r) {
            const RankDef& rd = rdefs[r];
            int nr = rd.nrows;
            rp_r[r] = rowptr_base + rpoff; rpoff += (size_t)nr + 1;
            cv_r[r] = cv_base + cvoff;
            int nb = (nr + SCAN_TILE - 1) / SCAN_TILE;
            hipMemsetAsync(counts, 0, (size_t)nr * sizeof(int), stream);
            for (int i = 0; i < rd.nmats; ++i) {
                int m = rd.mats[i];
                hist_kernel<<<(spn[m] + 255) / 256, 256, 0, stream>>>(spr[m], counts, spn[m]);
            }
            scan_phase1<<<nb, 256, 0, stream>>>(counts, bsums, nr);
            scan_phase2<<<1, 256, 0, stream>>>(bsums, nb);
            scan_phase3<<<nb, 256, 0, stream>>>(counts, bsums, rp_r[r], cursor, nr);
            set_total_kernel<<<1, 1, 0, stream>>>(rp_r[r] + nr, bsums + nb);
            for (int i = 0; i < rd.nmats; ++i) {
                int m = rd.mats[i];
                scatter_kernel<<<(spn[m] + 255) / 256, 256, 0, stream>>>(
                    spr[m], spc[m], spv[m], cursor, cv_r[r], spn[m], XB[m]);
                cvoff += (size_t)spn[m];
            }
        }
    }

    // ---- 4 layers: 7 projections + 3 gathers each ----
    for (int l = 0; l < 4; ++l) {
        const float* Wl = (l == 0) ? W1 : W234 + (size_t)(l - 1) * 7 * 32 * 32;
        const size_t wst = (l == 0) ? (size_t)64 * 32 : (size_t)32 * 32;
        for (int m = 0; m < 7; ++m) {
            const float* Wm = Wl + (size_t)wk_mat[m] * wst;
            __half* o = XWbuf + (size_t)XB[m] * 32;
            int n = srcrows_mat[m];
            if (l == 0) {
                const __half* x = Xh64 + (size_t)srcbase_mat[m] * 64;
                xw_kernel<64><<<4096, 256, 0, stream>>>(x, Wm, o, n);
            } else {
                const __half* x = act + (size_t)srcbase_mat[m] * 32;
                xw_kernel<32><<<4096, 256, 0, stream>>>(x, Wm, o, n);
            }
        }
        gather_kernel<<<(int)(((size_t)N0C * 32 + 255) / 256), 256, 0, stream>>>(
            rp_r[0], cv_r[0], XWbuf, act, AB0, 0.5f, N0C);
        gather_kernel<<<(int)(((size_t)N1C * 32 + 255) / 256), 256, 0, stream>>>(
            rp_r[1], cv_r[1], XWbuf, act, AB1, 1.f / 3.f, N1C);
        gather_kernel<<<(int)(((size_t)N2C * 32 + 255) / 256), 256, 0, stream>>>(
            rp_r[2], cv_r[2], XWbuf, act, AB2, 0.5f, N2C);
    }

    hipMemsetAsync(sums, 0, (size_t)(NGC * D + NGC) * sizeof(float), stream);
    {
        int groups = (N1C + 511) / 512;
        int blocks = (groups + 7) / 8;
        pool_kernel<<<blocks, 256, 0, stream>>>(act + (size_t)AB1 * 32, batch1, sums, cnt, N1C);
    }
    head_kernel<<<1, 128, 0, stream>>>(sums, cnt, mlp1_w, mlp1_b, mlp2_w, mlp2_b, out);
}